// Round 1
// baseline (2044.954 us; speedup 1.0000x reference)
//
#include <hip/hip_runtime.h>
#include <cmath>

// ============================================================================
// DPRNN block (intra BiGRU + inter Skip-GRU), all fp32.
// NUMERICS NOTE: inter skip-GRU has a binary gate round(sigmoid(h@Wp)) whose
// pre-activation std ~0.2; bf16 anywhere upstream flips gates (error 1.0).
// Hence full fp32 faithfulness everywhere this round.
// WS layout: [xw region | rnn region]; intra_out is stored in d_out region 0.
// 1-chunk path needs ws >= 400 MiB; otherwise auto-chunks (slower, correct).
// ============================================================================

__device__ __forceinline__ float sigf(float x) { return 1.0f / (1.0f + expf(-x)); }

// ---------------------------------------------------------------- fill ones
__global__ __launch_bounds__(256) void k_fill_ones(float* __restrict__ p, int n) {
  int i = blockIdx.x * 256 + threadIdx.x;
  if (i < n) p[i] = 1.0f;
}

// ---------------------------------------------------------------- GEMM (xw precompute)
// C[local_row][N] = gather_A[M0+row][0..K) @ Bm[K][N] + bias[N]
enum { MA_X_FWD = 0, MA_X_BWD = 1, MA_INTER = 2 };

template <int MODE>
__global__ __launch_bounds__(256) void k_gemm_xw(
    const float* __restrict__ A0, const float* __restrict__ A1,
    const float* __restrict__ Bm, const float* __restrict__ bias,
    float* __restrict__ Cm, long M0, int N, int K, int KT)
{
  __shared__ float As[16][68];
  __shared__ float Bs[16][68];
  const int tid = threadIdx.x;
  const int tx = tid & 15, ty = tid >> 4;
  const long row0g = M0 + (long)blockIdx.x * 64;
  const int col0 = blockIdx.y * 64;
  const int lr = tid >> 2;          // A-load row 0..63
  const int lk4 = (tid & 3) * 4;    // A-load k group
  const int bk = tid >> 4;          // B-load k 0..15
  const int bc4 = (tid & 15) * 4;   // B-load col group
  float acc[4][4];
#pragma unroll
  for (int i = 0; i < 4; ++i)
#pragma unroll
    for (int j = 0; j < 4; ++j) acc[i][j] = 0.f;

  for (int kt = 0; kt < KT; ++kt) {
    const int k0 = kt * 16;
    // ---- A tile (gathered) ----
    {
      const long rg = row0g + lr;
      float v0, v1, v2, v3;
      if (MODE == MA_X_FWD) {
        const float4 a4 = *reinterpret_cast<const float4*>(&A0[rg * 128 + k0 + lk4]);
        v0 = a4.x; v1 = a4.y; v2 = a4.z; v3 = a4.w;
      } else if (MODE == MA_X_BWD) {
        const long s = rg >> 6; const int t = (int)(rg & 63);
        const float4 a4 =
            *reinterpret_cast<const float4*>(&A0[(s * 64 + (63 - t)) * 128 + k0 + lk4]);
        v0 = a4.x; v1 = a4.y; v2 = a4.z; v3 = a4.w;
      } else {  // MA_INTER: rows (n,l), cols: intra_out[..] then scale, zero-pad
        const long n = rg / 200; const int l = (int)(rg - n * 200);
        const long bq = n >> 6; const int w = (int)(n & 63);
        const long rowc = (bq * 200 + l) * 64 + w;
        const long base = rowc * 128;
        float vv[4];
#pragma unroll
        for (int i = 0; i < 4; ++i) {
          const int k = k0 + lk4 + i;
          vv[i] = (k < 128) ? A0[base + k] : ((k == 128) ? A1[rowc] : 0.f);
        }
        v0 = vv[0]; v1 = vv[1]; v2 = vv[2]; v3 = vv[3];
      }
      As[lk4 + 0][lr] = v0;
      As[lk4 + 1][lr] = v1;
      As[lk4 + 2][lr] = v2;
      As[lk4 + 3][lr] = v3;
    }
    // ---- B tile ----
    {
      const int k = k0 + bk;
      float4 b4 = make_float4(0.f, 0.f, 0.f, 0.f);
      if (k < K) b4 = *reinterpret_cast<const float4*>(&Bm[(long)k * N + col0 + bc4]);
      *reinterpret_cast<float4*>(&Bs[bk][bc4]) = b4;
    }
    __syncthreads();
#pragma unroll
    for (int kk = 0; kk < 16; ++kk) {
      const float4 a4 = *reinterpret_cast<const float4*>(&As[kk][ty * 4]);
      const float4 b4 = *reinterpret_cast<const float4*>(&Bs[kk][tx * 4]);
      const float av[4] = {a4.x, a4.y, a4.z, a4.w};
      const float bv[4] = {b4.x, b4.y, b4.z, b4.w};
#pragma unroll
      for (int i = 0; i < 4; ++i)
#pragma unroll
        for (int j = 0; j < 4; ++j) acc[i][j] = fmaf(av[i], bv[j], acc[i][j]);
    }
    __syncthreads();
  }
  const float4 bi4 = *reinterpret_cast<const float4*>(&bias[col0 + tx * 4]);
  const float bv[4] = {bi4.x, bi4.y, bi4.z, bi4.w};
#pragma unroll
  for (int i = 0; i < 4; ++i) {
    const long rl = (long)blockIdx.x * 64 + ty * 4 + i;  // chunk-local row
    float4 o;
    o.x = acc[i][0] + bv[0];
    o.y = acc[i][1] + bv[1];
    o.z = acc[i][2] + bv[2];
    o.w = acc[i][3] + bv[3];
    *reinterpret_cast<float4*>(&Cm[rl * (long)N + col0 + tx * 4]) = o;
  }
}

// ---------------------------------------------------------------- intra GRU
// One direction per blockIdx.y; 8 sequences per block; U (64x192) in LDS.
__global__ __launch_bounds__(256, 2) void k_gru_intra(
    const float* __restrict__ xwf, const float* __restrict__ xwb,
    const float* __restrict__ Uf, const float* __restrict__ Ub,
    float* __restrict__ rnn, int nseq)
{
  const int dir = blockIdx.y;
  const float* __restrict__ xw = dir ? xwb : xwf;
  const float* __restrict__ U = dir ? Ub : Uf;
  __shared__ float Us[64 * 192];
  __shared__ float hs[8][64];
  __shared__ float zs[8][64];
  __shared__ float rhs[8][64];
  const int tid = threadIdx.x;
#pragma unroll
  for (int i = 0; i < 12; ++i) {
    *reinterpret_cast<float4*>(&Us[(tid + i * 256) * 4]) =
        *reinterpret_cast<const float4*>(&U[(tid + i * 256) * 4]);
  }
  reinterpret_cast<float*>(hs)[tid] = 0.f;
  reinterpret_cast<float*>(hs)[tid + 256] = 0.f;
  __syncthreads();
  const int sA = tid >> 5;   // sequence slot 0..7
  const int cA = tid & 31;   // col group
  const long s0 = (long)blockIdx.x * 8;
  const long xbase = (s0 + sA) * 64;
  // prefetch xw for t=0
  float4 xzr = *reinterpret_cast<const float4*>(&xw[(xbase + 0) * 192 + 4 * cA]);
  float2 xh = *reinterpret_cast<const float2*>(&xw[(xbase + 0) * 192 + 128 + 2 * cA]);
  for (int t = 0; t < 64; ++t) {
    float4 xzr_n = make_float4(0.f, 0.f, 0.f, 0.f);
    float2 xh_n = make_float2(0.f, 0.f);
    if (t < 63) {
      xzr_n = *reinterpret_cast<const float4*>(&xw[(xbase + t + 1) * 192 + 4 * cA]);
      xh_n = *reinterpret_cast<const float2*>(&xw[(xbase + t + 1) * 192 + 128 + 2 * cA]);
    }
    // ---- phase A: dots over h for z (cols 0..63) and r (cols 64..127) ----
    float a0 = 0.f, a1 = 0.f, a2 = 0.f, a3 = 0.f;
#pragma unroll
    for (int k4 = 0; k4 < 16; ++k4) {
      const float4 h4 = *reinterpret_cast<const float4*>(&hs[sA][4 * k4]);
      const float hv[4] = {h4.x, h4.y, h4.z, h4.w};
#pragma unroll
      for (int i = 0; i < 4; ++i) {
        const float4 u4 =
            *reinterpret_cast<const float4*>(&Us[(4 * k4 + i) * 192 + 4 * cA]);
        a0 = fmaf(hv[i], u4.x, a0);
        a1 = fmaf(hv[i], u4.y, a1);
        a2 = fmaf(hv[i], u4.z, a2);
        a3 = fmaf(hv[i], u4.w, a3);
      }
    }
    if (cA < 16) {  // z cols 4cA..4cA+3
      float4 zq;
      zq.x = sigf(xzr.x + a0);
      zq.y = sigf(xzr.y + a1);
      zq.z = sigf(xzr.z + a2);
      zq.w = sigf(xzr.w + a3);
      *reinterpret_cast<float4*>(&zs[sA][4 * cA]) = zq;
    } else {  // r cols, j0 = 4cA-64
      const int j0 = 4 * cA - 64;
      const float4 h4 = *reinterpret_cast<const float4*>(&hs[sA][j0]);
      float4 rq;
      rq.x = sigf(xzr.x + a0) * h4.x;
      rq.y = sigf(xzr.y + a1) * h4.y;
      rq.z = sigf(xzr.z + a2) * h4.z;
      rq.w = sigf(xzr.w + a3) * h4.w;
      *reinterpret_cast<float4*>(&rhs[sA][j0]) = rq;
    }
    __syncthreads();
    // ---- phase B: hh dots over r*h (cols 128 + 2cA, +1) ----
    float b0 = 0.f, b1 = 0.f;
#pragma unroll
    for (int k4 = 0; k4 < 16; ++k4) {
      const float4 r4 = *reinterpret_cast<const float4*>(&rhs[sA][4 * k4]);
      const float rv[4] = {r4.x, r4.y, r4.z, r4.w};
#pragma unroll
      for (int i = 0; i < 4; ++i) {
        const float2 u2 =
            *reinterpret_cast<const float2*>(&Us[(4 * k4 + i) * 192 + 128 + 2 * cA]);
        b0 = fmaf(rv[i], u2.x, b0);
        b1 = fmaf(rv[i], u2.y, b1);
      }
    }
    {
      const int j0 = 2 * cA;
      const float hh0 = tanhf(xh.x + b0);
      const float hh1 = tanhf(xh.y + b1);
      const float z0 = zs[sA][j0], z1 = zs[sA][j0 + 1];
      const float ho0 = hs[sA][j0], ho1 = hs[sA][j0 + 1];
      const float hn0 = z0 * ho0 + (1.f - z0) * hh0;
      const float hn1 = z1 * ho1 + (1.f - z1) * hh1;
      hs[sA][j0] = hn0;
      hs[sA][j0 + 1] = hn1;
      const int tt = dir ? (63 - t) : t;
      float2 st; st.x = hn0; st.y = hn1;
      *reinterpret_cast<float2*>(
          &rnn[((s0 + sA) * 64 + tt) * 128 + dir * 64 + j0]) = st;
    }
    __syncthreads();
    xzr = xzr_n; xh = xh_n;
  }
}

// ---------------------------------------------------------------- inter skip-GRU
// 4 sequences per block, 512 threads. Ui (128x384) fully register-resident:
// phase A (z,r cols 0..255): thread (cA=tid&255, ksA=tid>>8) holds 64-k slice.
// phase B (hh cols 256..383): thread (cB=tid&127, ksB=tid>>7) holds 32-k slice.
__global__ __launch_bounds__(512, 2) void k_gru_inter(
    const float* __restrict__ xw, const float* __restrict__ Ui,
    const float* __restrict__ Wp, const float* __restrict__ bp,
    float* __restrict__ rnn, float* __restrict__ gates, int chunk_s0)
{
  __shared__ float h_s[4][128];
  __shared__ float rh_s[4][128];
  __shared__ float z_s[4][128];
  __shared__ float pA[4][256];
  __shared__ float pB[3][4][128];
  __shared__ float wp_s[128];
  __shared__ float ut_s[4];
  __shared__ float u_s[4];
  const int tid = threadIdx.x;
  const int ksA = tid >> 8;   // 0..1
  const int cA = tid & 255;   // 0..255
  const int ksB = tid >> 7;   // 0..3
  const int cB = tid & 127;   // 0..127
  const int s0l = blockIdx.x * 4;  // chunk-local seq base
  float uzr[64];
#pragma unroll
  for (int k = 0; k < 64; ++k) uzr[k] = Ui[(long)(ksA * 64 + k) * 384 + cA];
  float u3[32];
#pragma unroll
  for (int k = 0; k < 32; ++k) u3[k] = Ui[(long)(ksB * 32 + k) * 384 + 256 + cB];
  reinterpret_cast<float*>(h_s)[tid] = 0.f;  // 512 = 4*128
  if (tid < 128) wp_s[tid] = Wp[tid];
  if (tid < 4) { ut_s[tid] = 1.0f; u_s[tid] = 1.0f; }
  const float bp0 = bp[0];
  __syncthreads();
  // prefetch xw t=0
  float xa[4] = {0.f, 0.f, 0.f, 0.f}, xb[4] = {0.f, 0.f, 0.f, 0.f};
  if (ksA == 0) {
#pragma unroll
    for (int s = 0; s < 4; ++s)
      xa[s] = xw[((long)(s0l + s) * 200 + 0) * 384 + cA];
  }
  if (ksB == 0) {
#pragma unroll
    for (int s = 0; s < 4; ++s)
      xb[s] = xw[((long)(s0l + s) * 200 + 0) * 384 + 256 + cB];
  }
  for (int t = 0; t < 200; ++t) {
    float xa_n[4] = {0.f, 0.f, 0.f, 0.f}, xb_n[4] = {0.f, 0.f, 0.f, 0.f};
    if (t < 199) {
      if (ksA == 0) {
#pragma unroll
        for (int s = 0; s < 4; ++s)
          xa_n[s] = xw[((long)(s0l + s) * 200 + t + 1) * 384 + cA];
      }
      if (ksB == 0) {
#pragma unroll
        for (int s = 0; s < 4; ++s)
          xb_n[s] = xw[((long)(s0l + s) * 200 + t + 1) * 384 + 256 + cB];
      }
    }
    // ---- phase A: z/r partial dots ----
    float accA[4];
#pragma unroll
    for (int s = 0; s < 4; ++s) {
      float a = 0.f;
#pragma unroll
      for (int k4 = 0; k4 < 16; ++k4) {
        const float4 hv =
            *reinterpret_cast<const float4*>(&h_s[s][ksA * 64 + 4 * k4]);
        a = fmaf(hv.x, uzr[4 * k4 + 0], a);
        a = fmaf(hv.y, uzr[4 * k4 + 1], a);
        a = fmaf(hv.z, uzr[4 * k4 + 2], a);
        a = fmaf(hv.w, uzr[4 * k4 + 3], a);
      }
      accA[s] = a;
    }
    if (ksA == 1) {
#pragma unroll
      for (int s = 0; s < 4; ++s) pA[s][cA] = accA[s];
    }
    __syncthreads();
    if (ksA == 0) {
#pragma unroll
      for (int s = 0; s < 4; ++s) {
        const float pre = xa[s] + accA[s] + pA[s][cA];
        if (cA < 128) {
          z_s[s][cA] = sigf(pre);
        } else {
          const float r = sigf(pre);
          rh_s[s][cA - 128] = r * h_s[s][cA - 128];
        }
      }
    }
    __syncthreads();
    // ---- phase B: hh partial dots over r*h ----
    float accB[4];
#pragma unroll
    for (int s = 0; s < 4; ++s) {
      float a = 0.f;
#pragma unroll
      for (int k4 = 0; k4 < 8; ++k4) {
        const float4 rv =
            *reinterpret_cast<const float4*>(&rh_s[s][ksB * 32 + 4 * k4]);
        a = fmaf(rv.x, u3[4 * k4 + 0], a);
        a = fmaf(rv.y, u3[4 * k4 + 1], a);
        a = fmaf(rv.z, u3[4 * k4 + 2], a);
        a = fmaf(rv.w, u3[4 * k4 + 3], a);
      }
      accB[s] = a;
    }
    if (ksB != 0) {
#pragma unroll
      for (int s = 0; s < 4; ++s) pB[ksB - 1][s][cB] = accB[s];
    }
    __syncthreads();
    if (ksB == 0) {
#pragma unroll
      for (int s = 0; s < 4; ++s) {
        const float pre = xb[s] + accB[s] + pB[0][s][cB] + pB[1][s][cB] + pB[2][s][cB];
        const float hh = tanhf(pre);
        const float z = z_s[s][cB];
        const float ho = h_s[s][cB];
        const float hn = z * ho + (1.f - z) * hh;
        const float u = u_s[s];  // binary 0/1 -> exact blend
        const float hq = u * hn + (1.f - u) * ho;
        h_s[s][cB] = hq;
        rnn[((long)(s0l + s) * 200 + t) * 128 + cB] = hq;
      }
    }
    __syncthreads();
    // ---- delta + gate state update (waves 0..3, one per sequence) ----
    {
      const int wv = tid >> 6, ln = tid & 63;
      if (wv < 4) {
        float p = h_s[wv][ln] * wp_s[ln] + h_s[wv][64 + ln] * wp_s[64 + ln];
        p += __shfl_xor(p, 32, 64);
        p += __shfl_xor(p, 16, 64);
        p += __shfl_xor(p, 8, 64);
        p += __shfl_xor(p, 4, 64);
        p += __shfl_xor(p, 2, 64);
        p += __shfl_xor(p, 1, 64);
        if (ln == 0) {
          const float delta = sigf(p + bp0);
          const float u = u_s[wv], ut = ut_s[wv];
          gates[(long)(chunk_s0 + s0l + wv) * 200 + t] = u;
          const float utn = u * delta + (1.f - u) * (ut + fminf(delta, 1.f - ut));
          ut_s[wv] = utn;
          u_s[wv] = rintf(utn);  // half-to-even, matches jnp.round
        }
      }
    }
    __syncthreads();
#pragma unroll
    for (int s = 0; s < 4; ++s) { xa[s] = xa_n[s]; xb[s] = xb_n[s]; }
  }
}

// ---------------------------------------------------------------- FC + LayerNorm + residual
// C tile = 32 rows x full 128 cols; row LN in-block; residual add; scatter store.
template <int OM>  // 0 = intra (direct rows), 1 = inter (transposed rows)
__global__ __launch_bounds__(256) void k_fcln(
    const float* __restrict__ A, const float* __restrict__ Wt,
    const float* __restrict__ bias, const float* __restrict__ gamma,
    const float* __restrict__ beta, const float* __restrict__ resid,
    float* __restrict__ dst, long M0)
{
  __shared__ float As[16][36];
  __shared__ float Bs[16][132];
  __shared__ float red0[32][33];
  __shared__ float red1[32][33];
  __shared__ float mu_s[32];
  __shared__ float rs_s[32];
  const int tid = threadIdx.x;
  const int tx = tid & 31, ty = tid >> 5;
  const long r0l = (long)blockIdx.x * 32;
  const int lr = tid >> 3;
  const int lk2 = (tid & 7) * 2;
  const int bkk = tid >> 4;
  const int bc8 = (tid & 15) * 8;
  float acc[4][4];
#pragma unroll
  for (int i = 0; i < 4; ++i)
#pragma unroll
    for (int j = 0; j < 4; ++j) acc[i][j] = 0.f;

  for (int kt = 0; kt < 8; ++kt) {
    const int k0 = kt * 16;
    const float2 a2 = *reinterpret_cast<const float2*>(&A[(r0l + lr) * 128 + k0 + lk2]);
    As[lk2][lr] = a2.x;
    As[lk2 + 1][lr] = a2.y;
    const float4 w0 = *reinterpret_cast<const float4*>(&Wt[(long)(k0 + bkk) * 128 + bc8]);
    const float4 w1 = *reinterpret_cast<const float4*>(&Wt[(long)(k0 + bkk) * 128 + bc8 + 4]);
    *reinterpret_cast<float4*>(&Bs[bkk][bc8]) = w0;
    *reinterpret_cast<float4*>(&Bs[bkk][bc8 + 4]) = w1;
    __syncthreads();
#pragma unroll
    for (int kk = 0; kk < 16; ++kk) {
      const float4 a4 = *reinterpret_cast<const float4*>(&As[kk][ty * 4]);
      const float4 b4 = *reinterpret_cast<const float4*>(&Bs[kk][tx * 4]);
      const float av[4] = {a4.x, a4.y, a4.z, a4.w};
      const float bv[4] = {b4.x, b4.y, b4.z, b4.w};
#pragma unroll
      for (int i = 0; i < 4; ++i)
#pragma unroll
        for (int j = 0; j < 4; ++j) acc[i][j] = fmaf(av[i], bv[j], acc[i][j]);
    }
    __syncthreads();
  }
  // bias then row statistics
  {
    const float4 bb4 = *reinterpret_cast<const float4*>(&bias[tx * 4]);
    const float bv[4] = {bb4.x, bb4.y, bb4.z, bb4.w};
#pragma unroll
    for (int i = 0; i < 4; ++i)
#pragma unroll
      for (int j = 0; j < 4; ++j) acc[i][j] += bv[j];
  }
#pragma unroll
  for (int i = 0; i < 4; ++i) {
    const float s = acc[i][0] + acc[i][1] + acc[i][2] + acc[i][3];
    const float q = acc[i][0] * acc[i][0] + acc[i][1] * acc[i][1] +
                    acc[i][2] * acc[i][2] + acc[i][3] * acc[i][3];
    red0[ty * 4 + i][tx] = s;
    red1[ty * 4 + i][tx] = q;
  }
  __syncthreads();
  if (tid < 32) {
    float s = 0.f, q = 0.f;
#pragma unroll
    for (int j = 0; j < 32; ++j) { s += red0[tid][j]; q += red1[tid][j]; }
    const float mu = s * (1.0f / 128.0f);
    const float var = q * (1.0f / 128.0f) - mu * mu;
    mu_s[tid] = mu;
    rs_s[tid] = 1.0f / sqrtf(var + 1e-8f);
  }
  __syncthreads();
  const float4 g4 = *reinterpret_cast<const float4*>(&gamma[tx * 4]);
  const float4 be4 = *reinterpret_cast<const float4*>(&beta[tx * 4]);
#pragma unroll
  for (int i = 0; i < 4; ++i) {
    const int rloc = ty * 4 + i;
    const long rg = M0 + r0l + rloc;  // global row
    long off;
    if (OM == 0) {
      off = rg * 128 + tx * 4;
    } else {
      const long n = rg / 200; const int l = (int)(rg - n * 200);
      const long bq = n >> 6; const int w = (int)(n & 63);
      off = ((bq * 200 + l) * 64 + w) * 128 + tx * 4;
    }
    const float4 r4 = *reinterpret_cast<const float4*>(&resid[off]);
    const float mu = mu_s[rloc], rs = rs_s[rloc];
    float4 o;
    o.x = (acc[i][0] - mu) * rs * g4.x + be4.x + r4.x;
    o.y = (acc[i][1] - mu) * rs * g4.y + be4.y + r4.y;
    o.z = (acc[i][2] - mu) * rs * g4.z + be4.z + r4.z;
    o.w = (acc[i][3] - mu) * rs * g4.w + be4.w + r4.w;
    *reinterpret_cast<float4*>(&dst[off]) = o;
  }
}

// ============================================================================
extern "C" void kernel_launch(void* const* d_in, const int* in_sizes, int n_in,
                              void* d_out, int out_size, void* d_ws, size_t ws_size,
                              hipStream_t stream)
{
  (void)in_sizes; (void)n_in; (void)out_size;
  const float* x    = (const float*)d_in[0];
  const float* scl  = (const float*)d_in[1];
  const float* Wf   = (const float*)d_in[2];
  const float* Uf   = (const float*)d_in[3];
  const float* bf   = (const float*)d_in[4];
  const float* Wb   = (const float*)d_in[5];
  const float* Ub   = (const float*)d_in[6];
  const float* bb   = (const float*)d_in[7];
  const float* Wfc1 = (const float*)d_in[8];
  const float* bfc1 = (const float*)d_in[9];
  const float* gam1 = (const float*)d_in[10];
  const float* bet1 = (const float*)d_in[11];
  const float* Wi   = (const float*)d_in[12];
  const float* Ui   = (const float*)d_in[13];
  const float* bi   = (const float*)d_in[14];
  const float* Wp   = (const float*)d_in[15];
  const float* bp   = (const float*)d_in[16];
  const float* Wfc2 = (const float*)d_in[17];
  const float* bfc2 = (const float*)d_in[18];
  const float* gam2 = (const float*)d_in[19];
  const float* bet2 = (const float*)d_in[20];

  float* outp  = (float*)d_out;
  float* io    = outp;                         // intra_out lives here
  float* onesp = outp + 26214400L;
  float* gates = outp + 26214400L + 12800L;
  float* ws    = (float*)d_ws;
  const long wsf = (long)(ws_size / sizeof(float));

  k_fill_ones<<<50, 256, 0, stream>>>(onesp, 12800);

  // ---------------- intra pass ----------------
  long cnI = (wsf / 32768L) & ~7L;   // per-seq ws: 2*64*192 (xw) + 64*128 (rnn)
  if (cnI > 3200) cnI = 3200;
  if (cnI < 8) cnI = 8;
  for (long s0 = 0; s0 < 3200; s0 += cnI) {
    const long cn = (3200 - s0 < cnI) ? (3200 - s0) : cnI;
    float* xwf = ws;
    float* xwb = ws + cn * 12288L;
    float* rnn = ws + cn * 24576L;
    const long M = cn * 64;
    dim3 gg((unsigned)(M / 64), 3);
    k_gemm_xw<MA_X_FWD><<<gg, 256, 0, stream>>>(x, nullptr, Wf, bf, xwf, s0 * 64, 192, 128, 8);
    k_gemm_xw<MA_X_BWD><<<gg, 256, 0, stream>>>(x, nullptr, Wb, bb, xwb, s0 * 64, 192, 128, 8);
    dim3 gr((unsigned)(cn / 8), 2);
    k_gru_intra<<<gr, 256, 0, stream>>>(xwf, xwb, Uf, Ub, rnn, (int)cn);
    k_fcln<0><<<(unsigned)(M / 32), 256, 0, stream>>>(rnn, Wfc1, bfc1, gam1, bet1, x, io, s0 * 64);
  }

  // ---------------- inter pass ----------------
  long cnE = (wsf / 102400L) & ~7L;  // per-seq ws: 200*384 (xw) + 200*128 (rnn)
  if (cnE > 1024) cnE = 1024;
  if (cnE < 8) cnE = 8;
  for (long s0 = 0; s0 < 1024; s0 += cnE) {
    const long cn = (1024 - s0 < cnE) ? (1024 - s0) : cnE;
    float* xwi = ws;
    float* rnn = ws + cn * 76800L;
    const long M = cn * 200;
    dim3 gg((unsigned)(M / 64), 6);
    k_gemm_xw<MA_INTER><<<gg, 256, 0, stream>>>(io, scl, Wi, bi, xwi, s0 * 200, 384, 129, 9);
    k_gru_inter<<<(unsigned)(cn / 4), 512, 0, stream>>>(xwi, Ui, Wp, bp, rnn, gates, (int)s0);
    k_fcln<1><<<(unsigned)(M / 32), 256, 0, stream>>>(rnn, Wfc2, bfc2, gam2, bet2, io, outp, s0 * 200);
  }
}